// Round 2
// baseline (1270.952 us; speedup 1.0000x reference)
//
#include <hip/hip_runtime.h>
#include <math.h>

// ---------------------------------------------------------------------------
// PhaseBiasedCrossAttention, MI355X/gfx950.  Round 2.
// [tab] fp64 cos/sin tables -> [proj] QKV projections (hi/lo bf16 split GEMM,
// unchanged from round 1) -> [attn] NEW: barrier-free per-wave two-pass online
// softmax; swapped QK^T (S^T in regs), f32x4 attn stores, PV via 1KB LDS
// bounce into mfma(V^T, P) -> [oproj] output projection (unchanged).
// ---------------------------------------------------------------------------

#define DEV __device__ __forceinline__

using f32x4 = __attribute__((ext_vector_type(4))) float;
using s16x8 = __attribute__((ext_vector_type(8))) short;
using s16x4 = __attribute__((ext_vector_type(4))) short;

constexpr int NB_ = 4;     // batch
constexpr int NH_ = 8;     // heads
constexpr int L_  = 2048;  // seq len (Lq == Lk)
constexpr int DM_ = 512;   // d_model
constexpr int DK_ = 64;    // head dim

DEV short f2bf(float f) {                 // fp32 -> bf16 (RNE), no NaNs here
  unsigned u = __float_as_uint(f);
  u += 0x7fffu + ((u >> 16) & 1u);
  return (short)(u >> 16);
}
DEV float bf2f(short s) {
  return __uint_as_float((unsigned)(unsigned short)s << 16);
}
DEV f32x4 mfma16(s16x8 a, s16x8 b, f32x4 c) {
  return __builtin_amdgcn_mfma_f32_16x16x32_bf16(a, b, c, 0, 0, 0);
}
DEV void split8(const float* f, s16x8& hi, s16x8& lo) {
#pragma unroll
  for (int j = 0; j < 8; ++j) {
    short h = f2bf(f[j]);
    hi[j] = h;
    lo[j] = f2bf(f[j] - bf2f(h));
  }
}

// --------------------------- cos/sin tables --------------------------------
__global__ void tab_kernel(const float* __restrict__ log_omega,
                           float* __restrict__ ctab, float* __restrict__ stab) {
  int h = blockIdx.y;
  int t = blockIdx.x * 256 + threadIdx.x;
  float om = expf(log_omega[h]);                    // matches ref fp32 exp
  double a = 6.283185307179586 * (double)om * (double)t;
  ctab[h * L_ + t] = (float)cos(a);
  stab[h * L_ + t] = (float)sin(a);
}

// ------------------- QKV projection GEMM (hi/lo split) ---------------------
// (unchanged from round 1 — proven correct; will be re-examined once counters
//  expose its cost relative to the new attn kernel)
__global__ __launch_bounds__(256, 2)
void proj_kernel(const float* __restrict__ Qin, const float* __restrict__ Kin,
                 const float* __restrict__ Vin,
                 const float* __restrict__ Wq, const float* __restrict__ bq,
                 const float* __restrict__ Wk, const float* __restrict__ bk,
                 const float* __restrict__ Wv, const float* __restrict__ bv,
                 short* __restrict__ Qh, short* __restrict__ Ql,
                 short* __restrict__ Kh, short* __restrict__ Kl,
                 short* __restrict__ Vt) {
  __shared__ short Ash[128 * 32], Asl[128 * 32], Bsh[128 * 32], Bsl[128 * 32];
  const int z = blockIdx.z;
  const float* X = (z == 0) ? Qin : (z == 1) ? Kin : Vin;
  const float* W = (z == 0) ? Wq : (z == 1) ? Wk : Wv;
  const float* bias = (z == 0) ? bq : (z == 1) ? bk : bv;
  const int m0 = blockIdx.x * 128, n0 = blockIdx.y * 128;
  const int t = threadIdx.x, lane = t & 63, w = t >> 6;
  const int wr = w >> 1, wc = w & 1;
  const int fr = lane & 15, fg = lane >> 4;

  f32x4 acc[4][4];
#pragma unroll
  for (int a = 0; a < 4; ++a)
#pragma unroll
    for (int b = 0; b < 4; ++b) acc[a][b] = f32x4{0.f, 0.f, 0.f, 0.f};

  for (int kt = 0; kt < 16; ++kt) {
    __syncthreads();
#pragma unroll
    for (int cc = 0; cc < 2; ++cc) {
      int cid = t + cc * 256;                 // chunk id over [128 rows][4 kblk]
      int row = cid >> 2, kb = cid & 3;
      float fa[8], fb[8];
      const float* ga = X + (size_t)(m0 + row) * DM_ + kt * 32 + kb * 8;
      const float* gb = W + (size_t)(n0 + row) * DM_ + kt * 32 + kb * 8;
      *(f32x4*)&fa[0] = *(const f32x4*)ga;  *(f32x4*)&fa[4] = *(const f32x4*)(ga + 4);
      *(f32x4*)&fb[0] = *(const f32x4*)gb;  *(f32x4*)&fb[4] = *(const f32x4*)(gb + 4);
      s16x8 hi, lo;
      split8(fa, hi, lo);
      ((s16x8*)Ash)[cid] = hi; ((s16x8*)Asl)[cid] = lo;
      split8(fb, hi, lo);
      ((s16x8*)Bsh)[cid] = hi; ((s16x8*)Bsl)[cid] = lo;
    }
    __syncthreads();
    s16x8 ah[4], al[4], bh_[4], bl_[4];
#pragma unroll
    for (int fm = 0; fm < 4; ++fm) {
      int r = wr * 64 + fm * 16 + fr;
      ah[fm] = ((const s16x8*)Ash)[r * 4 + fg];
      al[fm] = ((const s16x8*)Asl)[r * 4 + fg];
    }
#pragma unroll
    for (int fn = 0; fn < 4; ++fn) {
      int r = wc * 64 + fn * 16 + fr;
      bh_[fn] = ((const s16x8*)Bsh)[r * 4 + fg];
      bl_[fn] = ((const s16x8*)Bsl)[r * 4 + fg];
    }
#pragma unroll
    for (int fm = 0; fm < 4; ++fm)
#pragma unroll
      for (int fn = 0; fn < 4; ++fn) {
        acc[fm][fn] = mfma16(ah[fm], bh_[fn], acc[fm][fn]);
        acc[fm][fn] = mfma16(ah[fm], bl_[fn], acc[fm][fn]);
        acc[fm][fn] = mfma16(al[fm], bh_[fn], acc[fm][fn]);
      }
  }

  const float scale = (z == 0) ? 0.125f : 1.0f;   // fold 1/sqrt(DK) into Q
#pragma unroll
  for (int fn = 0; fn < 4; ++fn) {
    int C = n0 + wc * 64 + fn * 16 + fr;
    float bb = bias[C];
    int hh = C >> 6, d = C & 63;
#pragma unroll
    for (int fm = 0; fm < 4; ++fm) {
      int Rbase = m0 + wr * 64 + fm * 16 + fg * 4;
      if (z < 2) {
        short* Dh = (z == 0) ? Qh : Kh;
        short* Dl = (z == 0) ? Ql : Kl;
#pragma unroll
        for (int i = 0; i < 4; ++i) {
          int R = Rbase + i;
          int b = R >> 11, lq = R & 2047;
          float v = (acc[fm][fn][i] + bb) * scale;
          short h16 = f2bf(v);
          size_t off = ((size_t)(b * NH_ + hh) * L_ + lq) * DK_ + d;
          Dh[off] = h16;
          Dl[off] = f2bf(v - bf2f(h16));
        }
      } else {  // V: transposed [b,h,d,l], 4 consecutive l -> 8B packed store
        s16x4 p;
#pragma unroll
        for (int i = 0; i < 4; ++i) p[i] = f2bf(acc[fm][fn][i] + bb);
        int b = Rbase >> 11, lq = Rbase & 2047;
        size_t off = ((size_t)(b * NH_ + hh) * DK_ + d) * L_ + lq;
        *(s16x4*)(Vt + off) = p;
      }
    }
  }
}

// ------------------------------ attention ----------------------------------
// NEW: one wave = 16 q-rows x full 2048 k, two-pass online softmax, zero
// barriers.  WG = 4 waves = 64 consecutive q-rows of one (b,h).  Swapped
// QK^T: mfma(A=K-rows, B=Q-rows) -> lane (fr,fg) holds S^T[k=kc+4fg+i][q=q0+fr]
// so a q-row's k-values are 4-consecutive per lane -> f32x4 attn stores, and
// the row-reduce needs only shfl_xor(16,32).  PV: pack P to bf16, bounce
// through a 1KB per-wave XOR-swizzled LDS tile (write b64, read b128 frag),
// O^T = mfma(A=V^T-rows(d), B=P-rows(q)) accumulated over all k in-wave.
__global__ __launch_bounds__(256, 3)
void attn_kernel(const short* __restrict__ Qh, const short* __restrict__ Ql,
                 const short* __restrict__ Kh, const short* __restrict__ Kl,
                 const short* __restrict__ Vt,
                 const float* __restrict__ ctab, const float* __restrict__ stab,
                 float* __restrict__ attn, short* __restrict__ heads) {
  __shared__ short Pb[4][16 * 32];               // 4 waves x 1KB bounce tile
  // XCD-aware mapping: each XCD works through one (b,h) at a time so K/V stay
  // L2-resident (K hi+lo 512KB + V^T 256KB < 4MB per XCD).
  const int wgid = blockIdx.x;                   // 1024 WGs
  const int xcd = wgid & 7, j = wgid >> 3;       // j in [0,128)
  const int bh = ((j >> 5) << 3) + xcd;          // 4 bh per XCD, sequential
  const int qg = j & 31;
  const int w = threadIdx.x >> 6, lane = threadIdx.x & 63;
  const int fr = lane & 15, fg = lane >> 4;
  const int q0 = qg * 64 + w * 16;
  const int b = bh >> 3, h = bh & 7;

  // Q fragments (B operand): q = q0+fr, d = fg*8 + {0..7} and {32..39}
  const size_t qoff = ((size_t)bh * L_ + q0 + fr) * DK_ + fg * 8;
  const s16x8 qh0 = *(const s16x8*)(Qh + qoff), qh1 = *(const s16x8*)(Qh + qoff + 32);
  const s16x8 ql0 = *(const s16x8*)(Ql + qoff), ql1 = *(const s16x8*)(Ql + qoff + 32);
  const float cq = ctab[h * L_ + q0 + fr], sq = stab[h * L_ + q0 + fr];

  const short* Kbh = Kh + (size_t)bh * L_ * DK_;
  const short* Kbl = Kl + (size_t)bh * L_ * DK_;
  const short* Vbh = Vt + (size_t)bh * DK_ * L_;
  const float* ct = ctab + h * L_;
  const float* st = stab + h * L_;

  // One 16-k tile of S^T (+ phase bias).  Identical instruction DAG in both
  // passes -> bit-identical s -> (m,l) exactly consistent with pass-B values.
  auto qk = [&](int kc) -> f32x4 {
    size_t ko = (size_t)(kc + fr) * DK_ + fg * 8;
    s16x8 kh0 = *(const s16x8*)(Kbh + ko), kh1 = *(const s16x8*)(Kbh + ko + 32);
    s16x8 kl0 = *(const s16x8*)(Kbl + ko), kl1 = *(const s16x8*)(Kbl + ko + 32);
    f32x4 c = f32x4{0.f, 0.f, 0.f, 0.f};
    c = mfma16(kh0, qh0, c); c = mfma16(kh1, qh1, c);   // hi*hi
    c = mfma16(kl0, qh0, c); c = mfma16(kl1, qh1, c);   // lo(K)*hi(Q)
    c = mfma16(kh0, ql0, c); c = mfma16(kh1, ql1, c);   // hi(K)*lo(Q)
    f32x4 ck = *(const f32x4*)(ct + kc + fg * 4);
    f32x4 sk = *(const f32x4*)(st + kc + fg * 4);
#pragma unroll
    for (int i = 0; i < 4; ++i) c[i] += cq * ck[i] + sq * sk[i];
    return c;
  };

  // ---- pass A: online (m, l), no S storage ----
  float m = -3.0e38f, l = 0.f;
#pragma unroll 2
  for (int kc = 0; kc < L_; kc += 32) {
    f32x4 s0 = qk(kc), s1 = qk(kc + 16);
    float cm = fmaxf(fmaxf(fmaxf(s0[0], s0[1]), fmaxf(s0[2], s0[3])),
                     fmaxf(fmaxf(s1[0], s1[1]), fmaxf(s1[2], s1[3])));
    float mn = fmaxf(m, cm);
    float e = 0.f;
#pragma unroll
    for (int i = 0; i < 4; ++i) e += __expf(s0[i] - mn) + __expf(s1[i] - mn);
    l = l * __expf(m - mn) + e;
    m = mn;
  }
  // row q=fr lives on lanes {fr, fr+16, fr+32, fr+48}: butterfly over 2 hops
  {
    float m2 = fmaxf(m, __shfl_xor(m, 16));
    m2 = fmaxf(m2, __shfl_xor(m2, 32));
    l *= __expf(m - m2);
    l += __shfl_xor(l, 16);
    l += __shfl_xor(l, 32);
    m = m2;
  }
  const float invl = 1.0f / l;

  // ---- pass B: recompute S, normalize, store attn (f32x4) + PV ----
  short* buf = Pb[w];
  const int sw = fr & 3;                               // 16B-chunk XOR swizzle
  const int off0 = fr * 32 + (((fg >> 1) ^ sw) * 8) + (fg & 1) * 4;       // c=0
  const int off1 = fr * 32 + (((2 + (fg >> 1)) ^ sw) * 8) + (fg & 1) * 4; // c=1
  const int offr = fr * 32 + ((fg ^ sw) * 8);                             // read
  f32x4 ob[4];
#pragma unroll
  for (int dt = 0; dt < 4; ++dt) ob[dt] = f32x4{0.f, 0.f, 0.f, 0.f};

#pragma unroll 2
  for (int kc = 0; kc < L_; kc += 32) {
    f32x4 s0 = qk(kc), s1 = qk(kc + 16);
    f32x4 p0, p1;
#pragma unroll
    for (int i = 0; i < 4; ++i) {
      p0[i] = __expf(s0[i] - m) * invl;
      p1[i] = __expf(s1[i] - m) * invl;
    }
    float* arow = attn + ((size_t)bh * L_ + q0 + fr) * L_ + kc + fg * 4;
    *(f32x4*)arow = p0;                          // cols kc+4fg   .. +3
    *(f32x4*)(arow + 16) = p1;                   // cols kc+16+4fg.. +3
    // pack to bf16 and bounce through LDS to form the P A/B-frag layout
    s16x4 a0, a1;
#pragma unroll
    for (int i = 0; i < 4; ++i) { a0[i] = f2bf(p0[i]); a1[i] = f2bf(p1[i]); }
    *(s16x4*)(buf + off0) = a0;
    *(s16x4*)(buf + off1) = a1;
    s16x8 pa = *(const s16x8*)(buf + offr);      // P[q=fr][k=kc+8fg..+7]
#pragma unroll
    for (int dt = 0; dt < 4; ++dt) {
      const s16x8 va =
          *(const s16x8*)(Vbh + (size_t)(dt * 16 + fr) * L_ + kc + fg * 8);
      ob[dt] = mfma16(va, pa, ob[dt]);           // O^T[d][q] += V^T . P^T
    }
  }

  // ob[dt][i] = O[q=q0+fr][d=16dt+4fg+i] -> 8B packed stores
#pragma unroll
  for (int dt = 0; dt < 4; ++dt) {
    s16x4 hv;
#pragma unroll
    for (int i = 0; i < 4; ++i) hv[i] = f2bf(ob[dt][i]);
    *(s16x4*)(heads + ((size_t)b * L_ + q0 + fr) * DM_ + h * DK_ + dt * 16 +
              fg * 4) = hv;
  }
}

// ------------------------ output projection GEMM ---------------------------
__global__ __launch_bounds__(256, 2)
void oproj_kernel(const short* __restrict__ A, const float* __restrict__ W,
                  const float* __restrict__ bias, float* __restrict__ out) {
  __shared__ short As[128 * 32], Bs[128 * 32];
  const int m0 = blockIdx.x * 128, n0 = blockIdx.y * 128;
  const int t = threadIdx.x, lane = t & 63, w = t >> 6;
  const int wr = w >> 1, wc = w & 1;
  const int fr = lane & 15, fg = lane >> 4;

  f32x4 acc[4][4];
#pragma unroll
  for (int a = 0; a < 4; ++a)
#pragma unroll
    for (int b = 0; b < 4; ++b) acc[a][b] = f32x4{0.f, 0.f, 0.f, 0.f};

  for (int kt = 0; kt < 16; ++kt) {
    __syncthreads();
#pragma unroll
    for (int cc = 0; cc < 2; ++cc) {
      int cid = t + cc * 256;
      int row = cid >> 2, kb = cid & 3;
      ((s16x8*)As)[cid] =
          *(const s16x8*)(A + (size_t)(m0 + row) * DM_ + kt * 32 + kb * 8);
      const float* gb = W + (size_t)(n0 + row) * DM_ + kt * 32 + kb * 8;
      float fb[8];
      *(f32x4*)&fb[0] = *(const f32x4*)gb;  *(f32x4*)&fb[4] = *(const f32x4*)(gb + 4);
      s16x8 hb;
#pragma unroll
      for (int j = 0; j < 8; ++j) hb[j] = f2bf(fb[j]);
      ((s16x8*)Bs)[cid] = hb;
    }
    __syncthreads();
    s16x8 af[4], bf[4];
#pragma unroll
    for (int fm = 0; fm < 4; ++fm)
      af[fm] = ((const s16x8*)As)[(wr * 64 + fm * 16 + fr) * 4 + fg];
#pragma unroll
    for (int fn = 0; fn < 4; ++fn)
      bf[fn] = ((const s16x8*)Bs)[(wc * 64 + fn * 16 + fr) * 4 + fg];
#pragma unroll
    for (int fm = 0; fm < 4; ++fm)
#pragma unroll
      for (int fn = 0; fn < 4; ++fn) acc[fm][fn] = mfma16(af[fm], bf[fn], acc[fm][fn]);
  }
#pragma unroll
  for (int fn = 0; fn < 4; ++fn) {
    int C = n0 + wc * 64 + fn * 16 + fr;
    float bb = bias[C];
#pragma unroll
    for (int fm = 0; fm < 4; ++fm) {
      int Rbase = m0 + wr * 64 + fm * 16 + fg * 4;
#pragma unroll
      for (int i = 0; i < 4; ++i)
        out[(size_t)(Rbase + i) * DM_ + C] = acc[fm][fn][i] + bb;
    }
  }
}

// ---------------------------------------------------------------------------
extern "C" void kernel_launch(void* const* d_in, const int* in_sizes, int n_in,
                              void* d_out, int out_size, void* d_ws, size_t ws_size,
                              hipStream_t stream) {
  const float* Qin = (const float*)d_in[0];
  const float* Kin = (const float*)d_in[1];
  const float* Vin = (const float*)d_in[2];
  const float* Wq  = (const float*)d_in[3];
  const float* bq  = (const float*)d_in[4];
  const float* Wk  = (const float*)d_in[5];
  const float* bk  = (const float*)d_in[6];
  const float* Wv  = (const float*)d_in[7];
  const float* bv  = (const float*)d_in[8];
  const float* Wo  = (const float*)d_in[9];
  const float* bo  = (const float*)d_in[10];
  const float* lw  = (const float*)d_in[11];

  char* ws = (char*)d_ws;
  const size_t SZ = (size_t)NB_ * NH_ * L_ * DK_ * 2;  // 8 MiB per bf16 buffer
  short* Qh = (short*)(ws);
  short* Ql = (short*)(ws + SZ);
  short* Kh = (short*)(ws + 2 * SZ);
  short* Kl = (short*)(ws + 3 * SZ);
  short* Vt = (short*)(ws + 4 * SZ);
  short* heads = (short*)(ws + 5 * SZ);
  float* ctab = (float*)(ws + 6 * SZ);
  float* stab = ctab + NH_ * L_;

  float* out  = (float*)d_out;                       // [4,2048,512]
  float* attn = out + (size_t)NB_ * L_ * DM_;        // [4,8,2048,2048]

  tab_kernel<<<dim3(L_ / 256, NH_), 256, 0, stream>>>(lw, ctab, stab);
  proj_kernel<<<dim3(64, 4, 3), 256, 0, stream>>>(Qin, Kin, Vin, Wq, bq, Wk, bk,
                                                  Wv, bv, Qh, Ql, Kh, Kl, Vt);
  attn_kernel<<<dim3(1024), 256, 0, stream>>>(Qh, Ql, Kh, Kl, Vt, ctab, stab,
                                              attn, heads);
  oproj_kernel<<<dim3(64, 4), 256, 0, stream>>>(heads, Wo, bo, out);
}